// Round 1
// baseline (133.311 us; speedup 1.0000x reference)
//
#include <hip/hip_runtime.h>

// ---------------------------------------------------------------------------
// Additive attention weights:
//   k = key@Wk.T + bk ; q = (query@Wq.T + bq)/sqrt(D)
//   aq = q@Wc[:, :D].T ; ak = k@Wc[:, D:].T
//   logits[b,i,j] = sum_d Wl[d]*tanh(aq[b,i,d] + ak[b,j,d] + bc[d]) + bl
//   out = softmax_j(mask ? logits : -inf)   (fully-masked rows un-masked)
//
// Folding: tanh(x) = 1 - 2/(e^{2x}+1) = 1 - 2/(2^{C*x}+1), C = 2*log2(e).
// Uniform-in-j constants (bl, sum Wl) cancel in softmax, so
//   l_j = sum_d (-2*Wl[d]) * rcp(exp2(c2[d] + ak2[j][d]) + 1)
// with c2 = C*(aq+bc), ak2 = C*ak  (C folded into GEMM epilogues).
// ---------------------------------------------------------------------------

#define LOG2E     1.4426950408889634f
#define TWO_LOG2E 2.8853900817779268f
#define INV_SQRTD 0.04419417382415922f   // 1/sqrt(512)

typedef __attribute__((ext_vector_type(8))) short v8s;   // 8 bf16 (4 VGPRs)
typedef __attribute__((ext_vector_type(4))) float v4f;   // MFMA accumulator

#if __has_builtin(__builtin_amdgcn_exp2f)
#define EXP2(x) __builtin_amdgcn_exp2f(x)
#else
#define EXP2(x) exp2f(x)
#endif
#if __has_builtin(__builtin_amdgcn_rcpf)
#define RCP(x) __builtin_amdgcn_rcpf(x)
#else
#define RCP(x) (1.0f/(x))
#endif

__device__ inline unsigned int cvt2bf(float a, float b) {  // RNE f32->bf16 pair
  unsigned int ua = __float_as_uint(a);
  unsigned int ub = __float_as_uint(b);
  ua = (ua + 0x7FFFu + ((ua >> 16) & 1u)) >> 16;
  ub = (ub + 0x7FFFu + ((ub >> 16) & 1u)) >> 16;
  return ua | (ub << 16);
}

// Mask element-width detection: i32/f32 words of a 0/1 mask are in
// {0,1,0x3F800000}; packed bool-bytes are not (p ~ 1e-3 per word, ^64 ~ 0).
__global__ void detect_mask(const unsigned int* __restrict__ mw, int* __restrict__ flag) {
  unsigned int w = mw[threadIdx.x];
  bool ok = (w == 0u) || (w == 1u) || (w == 0x3F800000u);
  unsigned long long b = __ballot(ok);
  if (threadIdx.x == 0) *flag = (b == 0xFFFFFFFFFFFFFFFFull) ? 0 : 1; // 1 = bytes
}

// ---------------------------------------------------------------------------
// Generic C = (A @ W.T + bias) * scale, M=N=K=512, f32 in/out, bf16 MFMA.
// Two independent GEMMs packed per launch via blockIdx.z.
// BM=32, BN=64, BK=64, 256 threads (4 waves), 16x8x2 = 256 WGs = 1/CU.
// mode 0: out[m*512+n]; mode 1: out[(m>>8)*131072 + (n>>2)*1024 + (m&255)*4 + (n&3)]
//         (i.e. ak stored [b][d/4][j][4] so K3 reads a coalesced float4 per j)
// ---------------------------------------------------------------------------
__global__ __launch_bounds__(256) void gemm_bt(
    const float* __restrict__ A0, const float* __restrict__ W0, const float* __restrict__ b0,
    float s0, float* __restrict__ o0, int mode0, int ldw0,
    const float* __restrict__ A1, const float* __restrict__ W1, const float* __restrict__ b1,
    float s1, float* __restrict__ o1, int mode1, int ldw1)
{
  const int z = blockIdx.z;
  const float* A    = z ? A1 : A0;
  const float* W    = z ? W1 : W0;
  const float* bias = z ? b1 : b0;
  const float scale = z ? s1 : s0;
  float* out        = z ? o1 : o0;
  const int mode    = z ? mode1 : mode0;
  const int ldw     = z ? ldw1 : ldw0;

  const int m0 = blockIdx.x * 32;
  const int n0 = blockIdx.y * 64;
  const int tid = threadIdx.x;
  const int lane = tid & 63;
  const int wv = tid >> 6;

  // A: [32][64] bf16 (128B rows) @0 ; B: [64][64] bf16 @4096. XOR-swizzled.
  __shared__ unsigned char smem[12288];

  const int ar  = tid >> 3;  // A stage row 0..31
  const int akg = tid & 7;   // 8-elem k-group
  const int br  = tid >> 2;  // B stage row 0..63
  const int bq  = tid & 3;   // 16-elem k-group

  const int fr = lane & 15;            // frag row within 16
  const int fk = (lane >> 4) * 16;     // frag k byte offset within 32-k slice

  v4f acc0 = {0.f, 0.f, 0.f, 0.f};
  v4f acc1 = {0.f, 0.f, 0.f, 0.f};

  for (int kt = 0; kt < 8; ++kt) {
    const int k0 = kt * 64;
    const float* ap = A + (m0 + ar) * 512 + k0 + akg * 8;
    float4 av0 = *(const float4*)(ap);
    float4 av1 = *(const float4*)(ap + 4);
    const float* bp = W + (n0 + br) * ldw + k0 + bq * 16;
    float4 bv0 = *(const float4*)(bp);
    float4 bv1 = *(const float4*)(bp + 4);
    float4 bv2 = *(const float4*)(bp + 8);
    float4 bv3 = *(const float4*)(bp + 12);

    __syncthreads();  // previous iteration's frag reads done
    {
      int addr = (ar * 128 + akg * 16) ^ ((ar & 7) << 4);
      *(uint4*)(smem + addr) = make_uint4(cvt2bf(av0.x, av0.y), cvt2bf(av0.z, av0.w),
                                          cvt2bf(av1.x, av1.y), cvt2bf(av1.z, av1.w));
    }
    {
      int base = br * 128 + bq * 32;
      int addr  = 4096 + ((base)      ^ ((br & 7) << 4));
      int addr2 = 4096 + ((base + 16) ^ ((br & 7) << 4));
      *(uint4*)(smem + addr)  = make_uint4(cvt2bf(bv0.x, bv0.y), cvt2bf(bv0.z, bv0.w),
                                           cvt2bf(bv1.x, bv1.y), cvt2bf(bv1.z, bv1.w));
      *(uint4*)(smem + addr2) = make_uint4(cvt2bf(bv2.x, bv2.y), cvt2bf(bv2.z, bv2.w),
                                           cvt2bf(bv3.x, bv3.y), cvt2bf(bv3.z, bv3.w));
    }
    __syncthreads();

#pragma unroll
    for (int ks = 0; ks < 2; ++ks) {
      const int kb = ks * 64 + fk;
      const int rowb = wv * 16 + fr;
      int ra0 = ((fr)        * 128 + kb) ^ ((fr & 7) << 4);
      int ra1 = ((fr | 16)   * 128 + kb) ^ ((fr & 7) << 4);
      int rb  = 4096 + ((rowb * 128 + kb) ^ ((rowb & 7) << 4));
      v8s a0 = *(const v8s*)(smem + ra0);
      v8s a1 = *(const v8s*)(smem + ra1);
      v8s b  = *(const v8s*)(smem + rb);
      acc0 = __builtin_amdgcn_mfma_f32_16x16x32_bf16(a0, b, acc0, 0, 0, 0);
      acc1 = __builtin_amdgcn_mfma_f32_16x16x32_bf16(a1, b, acc1, 0, 0, 0);
    }
  }

  const int n = n0 + wv * 16 + (lane & 15);
  const int mbase = m0 + (lane >> 4) * 4;
  const float bn = bias ? bias[n] : 0.f;
#pragma unroll
  for (int r = 0; r < 4; ++r) {
    int m  = mbase + r;
    int m2 = m + 16;
    float v0 = (acc0[r] + bn) * scale;
    float v1 = (acc1[r] + bn) * scale;
    if (mode == 0) {
      out[m * 512 + n]  = v0;
      out[m2 * 512 + n] = v1;
    } else {
      out[(m  >> 8) * 131072 + (n >> 2) * 1024 + (m  & 255) * 4 + (n & 3)] = v0;
      out[(m2 >> 8) * 131072 + (n >> 2) * 1024 + (m2 & 255) * 4 + (n & 3)] = v1;
    }
  }
}

// ---------------------------------------------------------------------------
// K3: one WG per (b,i) row; thread = j. l_j = sum_d wl2[d]*rcp(exp2(c2+ak)+1),
// then masked softmax across the 256 threads.
// ---------------------------------------------------------------------------
__global__ __launch_bounds__(256) void attn_main(
    const float* __restrict__ c2, const float* __restrict__ ak4,
    const void* __restrict__ maskp, const float* __restrict__ Wl,
    const int* __restrict__ flagp, float* __restrict__ out)
{
  const int bx = blockIdx.x;   // b*256 + i
  const int j  = threadIdx.x;  // kv index

  __shared__ float2 cw[512];
  __shared__ float red[8];

  for (int dd = j; dd < 512; dd += 256)
    cw[dd] = make_float2(c2[bx * 512 + dd], -2.f * Wl[dd]);
  __syncthreads();

  const float* ak = ak4 + (bx >> 8) * 131072 + j * 4;
  float a0 = 0.f, a1 = 0.f, a2 = 0.f, a3 = 0.f;
#pragma unroll 8
  for (int db = 0; db < 128; ++db) {
    float4 v = *(const float4*)(ak + db * 1024);
    float2 p0 = cw[db * 4 + 0], p1 = cw[db * 4 + 1];
    float2 p2 = cw[db * 4 + 2], p3 = cw[db * 4 + 3];
    a0 += p0.y * RCP(EXP2(p0.x + v.x) + 1.f);
    a1 += p1.y * RCP(EXP2(p1.x + v.y) + 1.f);
    a2 += p2.y * RCP(EXP2(p2.x + v.z) + 1.f);
    a3 += p3.y * RCP(EXP2(p3.x + v.w) + 1.f);
  }
  float l = (a0 + a1) + (a2 + a3);

  // mask (element width resolved on-device)
  const int midx = bx * 256 + j;
  int mv;
  if (*flagp) mv = ((const unsigned char*)maskp)[midx];
  else        mv = ((const int*)maskp)[midx];   // covers i32 and f32 (bits!=0)
  const bool msk = (mv != 0);
  const int any = __syncthreads_or(msk ? 1 : 0);
  const bool use = msk || (any == 0);           // fully-masked row -> unmask

  float lm = use ? l : -3.0e38f;
  float wmax = lm;
#pragma unroll
  for (int o = 32; o > 0; o >>= 1) wmax = fmaxf(wmax, __shfl_xor(wmax, o));
  const int wid = j >> 6;
  if ((j & 63) == 0) red[wid] = wmax;
  __syncthreads();
  const float M = fmaxf(fmaxf(red[0], red[1]), fmaxf(red[2], red[3]));

  float p = use ? EXP2((l - M) * LOG2E) : 0.f;
  float s = p;
#pragma unroll
  for (int o = 32; o > 0; o >>= 1) s += __shfl_xor(s, o);
  if ((j & 63) == 0) red[4 + wid] = s;
  __syncthreads();
  const float S = (red[4] + red[5]) + (red[6] + red[7]);

  out[midx] = p * RCP(S);
}

extern "C" void kernel_launch(void* const* d_in, const int* in_sizes, int n_in,
                              void* d_out, int out_size, void* d_ws, size_t ws_size,
                              hipStream_t stream) {
  const float* key   = (const float*)d_in[0];
  const float* query = (const float*)d_in[1];
  // d_in[2] (value), d_in[6] (W_v), d_in[7] (b_v), d_in[13] (b_l) are unused.
  const void*  mask  = d_in[3];
  const float* W_k   = (const float*)d_in[4];
  const float* b_k   = (const float*)d_in[5];
  const float* W_q   = (const float*)d_in[8];
  const float* b_q   = (const float*)d_in[9];
  const float* W_c   = (const float*)d_in[10];
  const float* b_c   = (const float*)d_in[11];
  const float* W_l   = (const float*)d_in[12];

  float* ws  = (float*)d_ws;
  float* q2  = ws;            // [512][512]  q/sqrt(D) projected
  float* k2  = ws + 262144;   // [512][512]  k projected
  float* c2  = ws + 524288;   // [512][512]  C*(aq + bc)
  float* ak4 = ws + 786432;   // [2][128][256][4]  C*ak, d-interleaved by 4
  int* flag  = (int*)(ws + 1048576);

  detect_mask<<<1, 64, 0, stream>>>((const unsigned int*)mask, flag);

  dim3 g(16, 8, 2);
  // K1: q2 = (query@Wq.T + bq)/sqrt(D);  k2 = key@Wk.T + bk
  gemm_bt<<<g, 256, 0, stream>>>(query, W_q, b_q, INV_SQRTD, q2, 0, 512,
                                 key,   W_k, b_k, 1.0f,      k2, 0, 512);
  // K2: c2 = C*(q2@Wc_l.T + bc);  ak4 = C*(k2@Wc_r.T)  (transposed layout)
  gemm_bt<<<g, 256, 0, stream>>>(q2, W_c,       b_c,     TWO_LOG2E, c2,  0, 1024,
                                 k2, W_c + 512, nullptr, TWO_LOG2E, ak4, 1, 1024);

  attn_main<<<512, 256, 0, stream>>>(c2, ak4, mask, W_l, flag, (float*)d_out);
}